// Round 9
// baseline (240.579 us; speedup 1.0000x reference)
//
#include <hip/hip_runtime.h>

typedef _Float16 f16x8 __attribute__((ext_vector_type(8)));
typedef _Float16 f16x4 __attribute__((ext_vector_type(4)));
typedef _Float16 f16x2 __attribute__((ext_vector_type(2)));
typedef float    f32x4 __attribute__((ext_vector_type(4)));
typedef float    f32x4v __attribute__((ext_vector_type(4)));   // plain vec for nontemporal builtins

// ---------------- workspace layout (bytes) ----------------
#define EMBH_OFF  0ULL
#define CTXH_OFF  102400000ULL
#define APH_OFF   127565824ULL
#define WH_OFF    138051584ULL
#define WPH_OFF   138706944ULL
#define HEAD_OFF  139444224ULL
#define PROP_OFF  149274624ULL
#define NIDX_OFF  159105024ULL
#define PIDX_OFF  159203328ULL

__device__ __forceinline__ void gload16h(const _Float16* g, _Float16* l) {
    __builtin_amdgcn_global_load_lds(
        (const __attribute__((address_space(1))) unsigned int*)g,
        (__attribute__((address_space(3))) unsigned int*)l, 16, 0, 0);
}

// =============================================================
// Kernel 0: fp32 -> fp16 conversion (emb, W_out, W_prop w/ pad+reorder)
// =============================================================
__global__ __launch_bounds__(256) void conv_kernel(
    const float* __restrict__ emb, const float* __restrict__ W_out,
    const float* __restrict__ W_prop,
    _Float16* __restrict__ embh, _Float16* __restrict__ Wh, _Float16* __restrict__ Wph)
{
    const int N_EMB4 = 12800000;       // 100000*512/4
    const int N_WH4  = 81920;          // 320*1024/4
    const int N_WPH4 = 92160;          // 320*1152/4
    int stride = gridDim.x * 256;
    for (int id = blockIdx.x * 256 + threadIdx.x; id < N_EMB4 + N_WH4 + N_WPH4; id += stride) {
        f32x4 f; _Float16* dst;
        if (id < N_EMB4) {
            f = __builtin_nontemporal_load(((const f32x4v*)emb) + id);
            dst = embh + (size_t)id * 4;
        } else if (id < N_EMB4 + N_WH4) {
            int id2 = id - N_EMB4;
            int n = id2 >> 8, c4 = id2 & 255;
            f = (n < 300) ? __builtin_nontemporal_load(((const f32x4v*)W_out) + n * 256 + c4)
                          : (f32x4){0.f,0.f,0.f,0.f};
            dst = Wh + (size_t)id2 * 4;
        } else {
            int id3 = id - N_EMB4 - N_WH4;
            int n = id3 / 288, c4 = id3 - n * 288;
            if (n >= 300 || (c4 >= 150 && c4 < 160)) f = (f32x4){0.f,0.f,0.f,0.f};
            else if (c4 < 150) f = __builtin_nontemporal_load(((const f32x4v*)W_prop) + n * 278 + c4);
            else               f = __builtin_nontemporal_load(((const f32x4v*)W_prop) + n * 278 + c4 - 10);
            dst = Wph + (size_t)id3 * 4;
        }
        f16x4 h = { (_Float16)f.x, (_Float16)f.y, (_Float16)f.z, (_Float16)f.w };
        *(f16x4*)dst = h;
    }
}

// =============================================================
// Kernel A: gather + online-softmax attention (fp16 table).
// Neighbors processed in ASCENDING index order (bitonic sort of
// packed (idx<<5|pos) across lanes) -> all resident waves sweep
// the table in quantile-locked bands -> L2-friendly gather.
// Online softmax is permutation-invariant; v[pos] applied exactly.
// =============================================================
__global__ __launch_bounds__(256) void attend_kernel(
    const int* __restrict__ inputs,        // (4096,2,32)
    const int* __restrict__ inputs_prop,   // (4096,2,3,32)
    const _Float16* __restrict__ embh,     // (100000,512) f16
    const float* __restrict__ v,           // (31,)
    _Float16* __restrict__ ctxh,           // (24576,512) f16
    int* __restrict__ nidx, int* __restrict__ pidx,
    _Float16* __restrict__ Aph)            // (8192,640) f16
{
    int w    = blockIdx.x * 4 + (threadIdx.x >> 6);
    int lane = threadIdx.x & 63;
    int h = w >> 12;         // 0..5
    int b = w & 4095;

    int base, i = 0;
    const int* ip;
    if (h < 2) { base = (b * 2 + h) * 32; ip = inputs; }
    else {
        i = (h - 2) >> 1;
        int s = 1 + ((h - 2) & 1);
        base = ((b * 2 + i) * 3 + s) * 32;
        ip = inputs_prop;
    }

    int myidx = 0;
    if (lane < 32) myidx = ip[base + lane];
    int idx0 = __shfl(myidx, 0);
    if (lane == 0) {
        nidx[w] = idx0;
        if (h == 2 || h == 4) pidx[i * 4096 + b] = inputs_prop[((b * 2 + i) * 3) * 32];
    }

    // pack neighbors (idx<<5 | origpos), pad with INT_MAX, bitonic sort asc
    int srcl   = (lane < 31) ? (lane + 1) : 0;
    int nbidx  = __shfl(myidx, srcl);
    int packed = (lane < 31) ? ((nbidx << 5) | lane) : 0x7FFFFFFF;
    #pragma unroll
    for (int k = 2; k <= 64; k <<= 1) {
        #pragma unroll
        for (int jj = k >> 1; jj > 0; jj >>= 1) {
            int vp = __shfl_xor(packed, jj);
            bool asc   = ((lane & k) == 0);
            bool lower = ((lane & jj) == 0);
            int mn = min(packed, vp), mx = max(packed, vp);
            packed = (asc == lower) ? mn : mx;
        }
    }
    float vv = (lane < 31) ? v[lane] : 0.0f;   // lane l holds v[l]

    const f16x8* e8 = (const f16x8*)embh;
    f16x8 n8 = e8[(size_t)idx0 * 64 + lane];

    // 4-deep pipeline over sorted neighbors
    f16x8 pe[4];
    #pragma unroll
    for (int t = 1; t <= 4; ++t) {
        int pk = __shfl(packed, t - 1);
        pe[(t - 1) & 3] = e8[(size_t)(pk >> 5) * 64 + lane];
    }

    float m = -3.0e38f, den = 0.0f;
    float c[8] = {0.f,0.f,0.f,0.f,0.f,0.f,0.f,0.f};

    #pragma unroll
    for (int t = 1; t < 32; ++t) {
        const int slot = (t - 1) & 3;
        f16x8 ev = pe[slot];
        int pkc = __shfl(packed, t - 1);     // current (row,pos)
        if (t + 4 < 32) {
            int pk = __shfl(packed, t + 3);  // prefetch row t+4
            pe[slot] = e8[(size_t)(pk >> 5) * 64 + lane];
        }
        float p = 0.0f;
        const f16x2* na = (const f16x2*)&n8;
        const f16x2* ea = (const f16x2*)&ev;
#if __has_builtin(__builtin_amdgcn_fdot2)
        #pragma unroll
        for (int q = 0; q < 4; ++q) p = __builtin_amdgcn_fdot2(ea[q], na[q], p, false);
#else
        #pragma unroll
        for (int q = 0; q < 8; ++q) p += (float)ev[q] * (float)n8[q];
#endif
        #pragma unroll
        for (int d = 1; d < 64; d <<= 1) p += __shfl_xor(p, d);

        float s = (p != 0.0f) ? p : -9999.0f;   // mask: scores==0 -> -NEG
        if (s - m > 8.0f) {                     // rare, wave-uniform rescale (T13)
            float scale = __expf(m - s);
            den *= scale;
            #pragma unroll
            for (int q = 0; q < 8; ++q) c[q] *= scale;
            m = s;
        }
        float e = __expf(s - m);
        den += e;
        float wj = __shfl(vv, pkc & 31);        // v[origpos]
        float we = wj * e;
        #pragma unroll
        for (int q = 0; q < 8; ++q) c[q] += we * (float)ev[q];
    }
    float inv = 1.0f / den;
    f16x8 co;
    #pragma unroll
    for (int q = 0; q < 8; ++q) co[q] = (_Float16)(c[q] * inv);
    *(f16x8*)(ctxh + (size_t)w * 512 + lane * 8) = co;

    // zero-fill Aph pad cols [600,640) once per prop row
    if ((h == 2 || h == 4) && lane < 5) {
        f16x8 z = {};
        *(f16x8*)(Aph + (size_t)(i * 4096 + b) * 640 + 600 + lane * 8) = z;
    }
}

// =============================================================
// Kernel B: head GEMM  Y[24576,320] = [node|ctx](f16) @ Wh^T + b
// BN=320 (full N): A staged ONCE. BM=64, BK=64, 4 waves, each
// wave = 16 rows x 320 cols (20 n-frags). XOR-swizzled LDS.
// =============================================================
__global__ __launch_bounds__(256) void gemm_head_kernel(
    const _Float16* __restrict__ embh, const _Float16* __restrict__ ctxh,
    const int* __restrict__ nidx, const _Float16* __restrict__ Wh,
    const float* __restrict__ bias, float* __restrict__ outf,
    _Float16* __restrict__ Aph)
{
    __shared__ _Float16 Ash[64 * 64];    // 8 KB
    __shared__ _Float16 Bsh[320 * 64];   // 40 KB
    __shared__ int sN[64];

    int t = threadIdx.x, lane = t & 63, wid = t >> 6;
    int m0 = blockIdx.x * 64;
    if (t < 64) sN[t] = nidx[m0 + t];
    __syncthreads();

    f32x4 acc[20];
    #pragma unroll
    for (int nf = 0; nf < 20; ++nf) acc[nf] = (f32x4){0.f,0.f,0.f,0.f};

    int rowq = lane >> 3, cq = lane & 7;
    int cqs = cq ^ rowq;                 // inverse swizzle on global source
    int l15 = lane & 15, hi = lane >> 4, l7 = lane & 7;

    for (int k0 = 0; k0 < 1024; k0 += 64) {
        #pragma unroll
        for (int qq = 0; qq < 12; ++qq) {
            int q = wid * 12 + qq;
            if (q < 8) {                 // A tile: 64 rows x 64 halves
                int row = q * 8 + rowq;
                if (k0 < 512) gload16h(embh + (size_t)sN[row] * 512 + k0 + cqs * 8, Ash + q * 512);
                else          gload16h(ctxh + (size_t)(m0 + row) * 512 + (k0 - 512) + cqs * 8, Ash + q * 512);
            } else {                     // B tile: 320 rows x 64 halves
                int j = q - 8;
                int row = j * 8 + rowq;
                gload16h(Wh + (size_t)row * 1024 + k0 + cqs * 8, Bsh + j * 512);
            }
        }
        __syncthreads();

        #pragma unroll
        for (int s = 0; s < 2; ++s) {
            int sw = ((s * 4 + hi) ^ l7) * 8;
            f16x8 a = *(const f16x8*)&Ash[(wid * 16 + l15) * 64 + sw];
            #pragma unroll
            for (int nf = 0; nf < 20; ++nf) {
                f16x8 bb = *(const f16x8*)&Bsh[(nf * 16 + l15) * 64 + sw];
                acc[nf] = __builtin_amdgcn_mfma_f32_16x16x32_f16(a, bb, acc[nf], 0, 0, 0);
            }
        }
        __syncthreads();
    }

    // epilogue: C/D layout col = lane&15, row = (lane>>4)*4 + reg
    int h = (m0 >> 12);                  // block-uniform (m0 is 64-aligned)
    #pragma unroll
    for (int nf = 0; nf < 20; ++nf) {
        int n = nf * 16 + l15;
        if (n >= 300) continue;
        int rowbase = m0 + wid * 16 + (hi << 2);
        float bv = bias[n];
        #pragma unroll
        for (int r = 0; r < 4; ++r) {
            float val = acc[nf][r] + bv;
            int mm = rowbase + r;
            if (h < 2) {
                outf[(size_t)mm * 300 + n] = val;
            } else {
                int i = (h - 2) >> 1;
                int col = ((h - 2) & 1) ? 300 + n : n;
                Aph[(size_t)(i * 4096 + (mm & 4095)) * 640 + col] = (_Float16)val;
            }
        }
    }
}

// =============================================================
// Kernel C: prop GEMM  P[8192,320] = [dom|rng|pad|prp](f16) @ Wph^T + b
// BN=320, BM=32, K=1152. 4 waves as 2M x 2N (16 rows x 160 cols each).
// =============================================================
__global__ __launch_bounds__(256) void gemm_prop_kernel(
    const _Float16* __restrict__ Aph, const int* __restrict__ pidx,
    const _Float16* __restrict__ embh, const _Float16* __restrict__ Wph,
    const float* __restrict__ bias, float* __restrict__ outf)
{
    __shared__ _Float16 Ash[32 * 64];    // 4 KB
    __shared__ _Float16 Bsh[320 * 64];   // 40 KB
    __shared__ int sPid[32];

    int t = threadIdx.x, lane = t & 63, wid = t >> 6;
    int wm = wid >> 1, wn = wid & 1;
    int m0 = blockIdx.x * 32;
    if (t < 32) {
        int mm = m0 + t;
        sPid[t] = pidx[(mm >> 12) * 4096 + (mm & 4095)];
    }
    __syncthreads();

    f32x4 acc[10];
    #pragma unroll
    for (int nf = 0; nf < 10; ++nf) acc[nf] = (f32x4){0.f,0.f,0.f,0.f};

    int rowq = lane >> 3, cq = lane & 7;
    int cqs = cq ^ rowq;
    int l15 = lane & 15, hi = lane >> 4, l7 = lane & 7;

    for (int k0 = 0; k0 < 1152; k0 += 64) {
        #pragma unroll
        for (int qq = 0; qq < 11; ++qq) {
            int q = wid * 11 + qq;
            if (q < 4) {                 // A tile: 32 rows
                int row = q * 8 + rowq;
                if (k0 < 640) gload16h(Aph + (size_t)(m0 + row) * 640 + k0 + cqs * 8, Ash + q * 512);
                else          gload16h(embh + (size_t)sPid[row] * 512 + (k0 - 640) + cqs * 8, Ash + q * 512);
            } else if (q < 44) {         // B tile: 320 rows
                int j = q - 4;
                int row = j * 8 + rowq;
                gload16h(Wph + (size_t)row * 1152 + k0 + cqs * 8, Bsh + j * 512);
            }
        }
        __syncthreads();

        #pragma unroll
        for (int s = 0; s < 2; ++s) {
            int sw = ((s * 4 + hi) ^ l7) * 8;
            f16x8 a = *(const f16x8*)&Ash[(wm * 16 + l15) * 64 + sw];
            #pragma unroll
            for (int nf = 0; nf < 10; ++nf) {
                f16x8 bb = *(const f16x8*)&Bsh[((wn * 10 + nf) * 16 + l15) * 64 + sw];
                acc[nf] = __builtin_amdgcn_mfma_f32_16x16x32_f16(a, bb, acc[nf], 0, 0, 0);
            }
        }
        __syncthreads();
    }

    #pragma unroll
    for (int nf = 0; nf < 10; ++nf) {
        int n = wn * 160 + nf * 16 + l15;
        if (n >= 300) continue;
        int rowbase = m0 + wm * 16 + (hi << 2);
        float bv = bias[n];
        #pragma unroll
        for (int r = 0; r < 4; ++r)
            outf[(size_t)(rowbase + r) * 300 + n] = acc[nf][r] + bv;
    }
}

// =============================================================
// Kernel D: cosines -> d_out[0:4096]=x_ent, [4096:8192]=x_prop
// =============================================================
__global__ __launch_bounds__(256) void cosine_kernel(
    const float* __restrict__ head_out,  // (8192,300) ent heads
    const float* __restrict__ prop_out,  // (8192,300)
    float* __restrict__ out)             // (8192,)
{
    int w    = blockIdx.x * 4 + (threadIdx.x >> 6);
    int lane = threadIdx.x & 63;
    const float *a, *b;
    if (w < 4096) {
        a = head_out + (size_t)w * 300;
        b = head_out + (size_t)(4096 + w) * 300;
    } else {
        int b2 = w - 4096;
        a = prop_out + (size_t)b2 * 300;
        b = prop_out + (size_t)(4096 + b2) * 300;
    }
    float ab = 0.f, aa = 0.f, bb = 0.f;
    for (int tt = lane; tt < 300; tt += 64) {
        float av = a[tt], bv = b[tt];
        ab += av * bv; aa += av * av; bb += bv * bv;
    }
    #pragma unroll
    for (int d = 1; d < 64; d <<= 1) {
        ab += __shfl_xor(ab, d);
        aa += __shfl_xor(aa, d);
        bb += __shfl_xor(bb, d);
    }
    if (lane == 0) {
        float na = fmaxf(sqrtf(aa), 1e-8f);
        float nb = fmaxf(sqrtf(bb), 1e-8f);
        out[w] = ab / (na * nb);
    }
}

extern "C" void kernel_launch(void* const* d_in, const int* in_sizes, int n_in,
                              void* d_out, int out_size, void* d_ws, size_t ws_size,
                              hipStream_t stream) {
    const int*   inputs      = (const int*)d_in[0];
    const int*   inputs_prop = (const int*)d_in[1];
    const float* emb         = (const float*)d_in[2];
    const float* W_out       = (const float*)d_in[3];
    const float* b_out       = (const float*)d_in[4];
    const float* v           = (const float*)d_in[5];
    const float* W_prop      = (const float*)d_in[6];
    const float* b_prop      = (const float*)d_in[7];
    float* out = (float*)d_out;

    char* ws = (char*)d_ws;
    _Float16* embh = (_Float16*)(ws + EMBH_OFF);
    _Float16* ctxh = (_Float16*)(ws + CTXH_OFF);
    _Float16* Aph  = (_Float16*)(ws + APH_OFF);
    _Float16* Wh   = (_Float16*)(ws + WH_OFF);
    _Float16* Wph  = (_Float16*)(ws + WPH_OFF);
    float* head_out = (float*)(ws + HEAD_OFF);
    float* prop_out = (float*)(ws + PROP_OFF);
    int*   nidx     = (int*)(ws + NIDX_OFF);
    int*   pidx     = (int*)(ws + PIDX_OFF);

    conv_kernel<<<8192, 256, 0, stream>>>(emb, W_out, W_prop, embh, Wh, Wph);
    attend_kernel<<<6144, 256, 0, stream>>>(inputs, inputs_prop, embh, v, ctxh, nidx, pidx, Aph);
    gemm_head_kernel<<<384, 256, 0, stream>>>(embh, ctxh, nidx, Wh, b_out, head_out, Aph);
    gemm_prop_kernel<<<256, 256, 0, stream>>>(Aph, pidx, embh, Wph, b_prop, prop_out);
    cosine_kernel<<<2048, 256, 0, stream>>>(head_out, prop_out, out);
}

// Round 10
// 238.076 us; speedup vs baseline: 1.0105x; 1.0105x over previous
//
#include <hip/hip_runtime.h>

typedef _Float16 f16x8 __attribute__((ext_vector_type(8)));
typedef _Float16 f16x4 __attribute__((ext_vector_type(4)));
typedef _Float16 f16x2 __attribute__((ext_vector_type(2)));
typedef float    f32x4 __attribute__((ext_vector_type(4)));
typedef float    f32x4v __attribute__((ext_vector_type(4)));   // plain vec for nontemporal builtins

// ---------------- workspace layout (bytes) ----------------
#define EMBH_OFF  0ULL
#define CTXH_OFF  102400000ULL
#define APH_OFF   127565824ULL
#define WH_OFF    138051584ULL
#define WPH_OFF   138706944ULL
#define HEAD_OFF  139444224ULL
#define PROP_OFF  149274624ULL
#define NIDX_OFF  159105024ULL
#define PIDX_OFF  159203328ULL

__device__ __forceinline__ void gload16h(const _Float16* g, _Float16* l) {
    __builtin_amdgcn_global_load_lds(
        (const __attribute__((address_space(1))) unsigned int*)g,
        (__attribute__((address_space(3))) unsigned int*)l, 16, 0, 0);
}

// =============================================================
// Kernel 0: fp32 -> fp16 conversion (emb, W_out, W_prop w/ pad+reorder)
// =============================================================
__global__ __launch_bounds__(256) void conv_kernel(
    const float* __restrict__ emb, const float* __restrict__ W_out,
    const float* __restrict__ W_prop,
    _Float16* __restrict__ embh, _Float16* __restrict__ Wh, _Float16* __restrict__ Wph)
{
    const int N_EMB4 = 12800000;       // 100000*512/4
    const int N_WH4  = 81920;          // 320*1024/4
    const int N_WPH4 = 92160;          // 320*1152/4
    int stride = gridDim.x * 256;
    for (int id = blockIdx.x * 256 + threadIdx.x; id < N_EMB4 + N_WH4 + N_WPH4; id += stride) {
        f32x4 f; _Float16* dst;
        if (id < N_EMB4) {
            f = __builtin_nontemporal_load(((const f32x4v*)emb) + id);
            dst = embh + (size_t)id * 4;
        } else if (id < N_EMB4 + N_WH4) {
            int id2 = id - N_EMB4;
            int n = id2 >> 8, c4 = id2 & 255;
            f = (n < 300) ? __builtin_nontemporal_load(((const f32x4v*)W_out) + n * 256 + c4)
                          : (f32x4){0.f,0.f,0.f,0.f};
            dst = Wh + (size_t)id2 * 4;
        } else {
            int id3 = id - N_EMB4 - N_WH4;
            int n = id3 / 288, c4 = id3 - n * 288;
            if (n >= 300 || (c4 >= 150 && c4 < 160)) f = (f32x4){0.f,0.f,0.f,0.f};
            else if (c4 < 150) f = __builtin_nontemporal_load(((const f32x4v*)W_prop) + n * 278 + c4);
            else               f = __builtin_nontemporal_load(((const f32x4v*)W_prop) + n * 278 + c4 - 10);
            dst = Wph + (size_t)id3 * 4;
        }
        f16x4 h = { (_Float16)f.x, (_Float16)f.y, (_Float16)f.z, (_Float16)f.w };
        *(f16x4*)dst = h;
    }
}

// =============================================================
// Kernel A: gather + online-softmax attention (fp16 table).
// fdot2 score path, deferred rescale, 4-deep prefetch (R8 form).
// =============================================================
__global__ __launch_bounds__(256) void attend_kernel(
    const int* __restrict__ inputs,        // (4096,2,32)
    const int* __restrict__ inputs_prop,   // (4096,2,3,32)
    const _Float16* __restrict__ embh,     // (100000,512) f16
    const float* __restrict__ v,           // (31,)
    _Float16* __restrict__ ctxh,           // (24576,512) f16
    int* __restrict__ nidx, int* __restrict__ pidx,
    _Float16* __restrict__ Aph)            // (8192,640) f16
{
    int w    = blockIdx.x * 4 + (threadIdx.x >> 6);
    int lane = threadIdx.x & 63;
    int h = w >> 12;         // 0..5
    int b = w & 4095;

    int base, i = 0;
    const int* ip;
    if (h < 2) { base = (b * 2 + h) * 32; ip = inputs; }
    else {
        i = (h - 2) >> 1;
        int s = 1 + ((h - 2) & 1);
        base = ((b * 2 + i) * 3 + s) * 32;
        ip = inputs_prop;
    }

    int myidx = 0;
    if (lane < 32) myidx = ip[base + lane];
    int idx0 = __shfl(myidx, 0);
    if (lane == 0) {
        nidx[w] = idx0;
        if (h == 2 || h == 4) pidx[i * 4096 + b] = inputs_prop[((b * 2 + i) * 3) * 32];
    }

    const f16x8* e8 = (const f16x8*)embh;
    f16x8 n8 = e8[(size_t)idx0 * 64 + lane];

    // 4-deep pipeline
    f16x8 pe[4];
    #pragma unroll
    for (int j = 1; j <= 4; ++j) {
        int ij = __shfl(myidx, j);
        pe[(j - 1) & 3] = e8[(size_t)ij * 64 + lane];
    }

    float m = -3.0e38f, den = 0.0f;
    float c[8] = {0.f,0.f,0.f,0.f,0.f,0.f,0.f,0.f};

    #pragma unroll
    for (int j = 1; j < 32; ++j) {
        const int slot = (j - 1) & 3;
        f16x8 ev = pe[slot];
        if (j + 4 < 32) {
            int ijn = __shfl(myidx, j + 4);
            pe[slot] = e8[(size_t)ijn * 64 + lane];
        }
        float p = 0.0f;
        const f16x2* na = (const f16x2*)&n8;
        const f16x2* ea = (const f16x2*)&ev;
#if __has_builtin(__builtin_amdgcn_fdot2)
        #pragma unroll
        for (int q = 0; q < 4; ++q) p = __builtin_amdgcn_fdot2(ea[q], na[q], p, false);
#else
        #pragma unroll
        for (int q = 0; q < 8; ++q) p += (float)ev[q] * (float)n8[q];
#endif
        #pragma unroll
        for (int d = 1; d < 64; d <<= 1) p += __shfl_xor(p, d);

        float s = (p != 0.0f) ? p : -9999.0f;   // mask: scores==0 -> -NEG
        if (s - m > 8.0f) {                     // rare, wave-uniform rescale (T13)
            float scale = __expf(m - s);
            den *= scale;
            #pragma unroll
            for (int q = 0; q < 8; ++q) c[q] *= scale;
            m = s;
        }
        float e = __expf(s - m);
        den += e;
        float we = v[j - 1] * e;
        #pragma unroll
        for (int q = 0; q < 8; ++q) c[q] += we * (float)ev[q];   // v_fma_mix
    }
    float inv = 1.0f / den;
    f16x8 co;
    #pragma unroll
    for (int q = 0; q < 8; ++q) co[q] = (_Float16)(c[q] * inv);
    *(f16x8*)(ctxh + (size_t)w * 512 + lane * 8) = co;

    // zero-fill Aph pad cols [600,640) once per prop row
    if ((h == 2 || h == 4) && lane < 5) {
        f16x8 z = {};
        *(f16x8*)(Aph + (size_t)(i * 4096 + b) * 640 + 600 + lane * 8) = z;
    }
}

// =============================================================
// Kernel B: head GEMM  Y[24576,320] = [node|ctx](f16) @ Wh^T + b
// BM=48, 192 threads (3 waves of 16 rows), grid 512 = 2 blocks/CU
// (perfect balance). BN=320 full-N: A staged once. XOR-swizzled LDS.
// Head-id computed PER ROW (48 doesn't divide 4096).
// =============================================================
__global__ __launch_bounds__(192) void gemm_head_kernel(
    const _Float16* __restrict__ embh, const _Float16* __restrict__ ctxh,
    const int* __restrict__ nidx, const _Float16* __restrict__ Wh,
    const float* __restrict__ bias, float* __restrict__ outf,
    _Float16* __restrict__ Aph)
{
    __shared__ _Float16 Ash[48 * 64];    // 6 KB
    __shared__ _Float16 Bsh[320 * 64];   // 40 KB
    __shared__ int sN[48];

    int t = threadIdx.x, lane = t & 63, wid = t >> 6;   // wid 0..2
    int m0 = blockIdx.x * 48;
    if (t < 48) sN[t] = nidx[m0 + t];
    __syncthreads();

    f32x4 acc[20];
    #pragma unroll
    for (int nf = 0; nf < 20; ++nf) acc[nf] = (f32x4){0.f,0.f,0.f,0.f};

    int rowq = lane >> 3, cq = lane & 7;
    int cqs = cq ^ rowq;                 // inverse swizzle on global source
    int l15 = lane & 15, hi = lane >> 4, l7 = lane & 7;

    for (int k0 = 0; k0 < 1024; k0 += 64) {
        #pragma unroll
        for (int qq = 0; qq < 16; ++qq) {
            int q = wid * 16 + qq;       // 0..47; 46 used (6 A + 40 B)
            if (q < 6) {                 // A tile: 48 rows x 64 halves
                int row = q * 8 + rowq;
                if (k0 < 512) gload16h(embh + (size_t)sN[row] * 512 + k0 + cqs * 8, Ash + q * 512);
                else          gload16h(ctxh + (size_t)(m0 + row) * 512 + (k0 - 512) + cqs * 8, Ash + q * 512);
            } else if (q < 46) {         // B tile: 320 rows x 64 halves
                int j = q - 6;
                int row = j * 8 + rowq;
                gload16h(Wh + (size_t)row * 1024 + k0 + cqs * 8, Bsh + j * 512);
            }
        }
        __syncthreads();

        #pragma unroll
        for (int s = 0; s < 2; ++s) {
            int sw = ((s * 4 + hi) ^ l7) * 8;
            f16x8 a = *(const f16x8*)&Ash[(wid * 16 + l15) * 64 + sw];
            #pragma unroll
            for (int nf = 0; nf < 20; ++nf) {
                f16x8 bb = *(const f16x8*)&Bsh[(nf * 16 + l15) * 64 + sw];
                acc[nf] = __builtin_amdgcn_mfma_f32_16x16x32_f16(a, bb, acc[nf], 0, 0, 0);
            }
        }
        __syncthreads();
    }

    // epilogue: C/D layout col = lane&15, row = (lane>>4)*4 + reg
    #pragma unroll
    for (int nf = 0; nf < 20; ++nf) {
        int n = nf * 16 + l15;
        if (n >= 300) continue;
        int rowbase = m0 + wid * 16 + (hi << 2);
        float bv = bias[n];
        #pragma unroll
        for (int r = 0; r < 4; ++r) {
            float val = acc[nf][r] + bv;
            int mm = rowbase + r;
            int h = mm >> 12;            // per-row (48 ∤ 4096)
            if (h < 2) {
                outf[(size_t)mm * 300 + n] = val;
            } else {
                int i = (h - 2) >> 1;
                int col = ((h - 2) & 1) ? 300 + n : n;
                Aph[(size_t)(i * 4096 + (mm & 4095)) * 640 + col] = (_Float16)val;
            }
        }
    }
}

// =============================================================
// Kernel C: prop GEMM  P[8192,320] = [dom|rng|pad|prp](f16) @ Wph^T + b
// BN=320, BM=32, K=1152. 4 waves as 2M x 2N (16 rows x 160 cols each).
// =============================================================
__global__ __launch_bounds__(256) void gemm_prop_kernel(
    const _Float16* __restrict__ Aph, const int* __restrict__ pidx,
    const _Float16* __restrict__ embh, const _Float16* __restrict__ Wph,
    const float* __restrict__ bias, float* __restrict__ outf)
{
    __shared__ _Float16 Ash[32 * 64];    // 4 KB
    __shared__ _Float16 Bsh[320 * 64];   // 40 KB
    __shared__ int sPid[32];

    int t = threadIdx.x, lane = t & 63, wid = t >> 6;
    int wm = wid >> 1, wn = wid & 1;
    int m0 = blockIdx.x * 32;
    if (t < 32) {
        int mm = m0 + t;
        sPid[t] = pidx[(mm >> 12) * 4096 + (mm & 4095)];
    }
    __syncthreads();

    f32x4 acc[10];
    #pragma unroll
    for (int nf = 0; nf < 10; ++nf) acc[nf] = (f32x4){0.f,0.f,0.f,0.f};

    int rowq = lane >> 3, cq = lane & 7;
    int cqs = cq ^ rowq;
    int l15 = lane & 15, hi = lane >> 4, l7 = lane & 7;

    for (int k0 = 0; k0 < 1152; k0 += 64) {
        #pragma unroll
        for (int qq = 0; qq < 11; ++qq) {
            int q = wid * 11 + qq;
            if (q < 4) {                 // A tile: 32 rows
                int row = q * 8 + rowq;
                if (k0 < 640) gload16h(Aph + (size_t)(m0 + row) * 640 + k0 + cqs * 8, Ash + q * 512);
                else          gload16h(embh + (size_t)sPid[row] * 512 + (k0 - 640) + cqs * 8, Ash + q * 512);
            } else if (q < 44) {         // B tile: 320 rows
                int j = q - 4;
                int row = j * 8 + rowq;
                gload16h(Wph + (size_t)row * 1152 + k0 + cqs * 8, Bsh + j * 512);
            }
        }
        __syncthreads();

        #pragma unroll
        for (int s = 0; s < 2; ++s) {
            int sw = ((s * 4 + hi) ^ l7) * 8;
            f16x8 a = *(const f16x8*)&Ash[(wm * 16 + l15) * 64 + sw];
            #pragma unroll
            for (int nf = 0; nf < 10; ++nf) {
                f16x8 bb = *(const f16x8*)&Bsh[((wn * 10 + nf) * 16 + l15) * 64 + sw];
                acc[nf] = __builtin_amdgcn_mfma_f32_16x16x32_f16(a, bb, acc[nf], 0, 0, 0);
            }
        }
        __syncthreads();
    }

    #pragma unroll
    for (int nf = 0; nf < 10; ++nf) {
        int n = wn * 160 + nf * 16 + l15;
        if (n >= 300) continue;
        int rowbase = m0 + wm * 16 + (hi << 2);
        float bv = bias[n];
        #pragma unroll
        for (int r = 0; r < 4; ++r)
            outf[(size_t)(rowbase + r) * 300 + n] = acc[nf][r] + bv;
    }
}

// =============================================================
// Kernel D: cosines -> d_out[0:4096]=x_ent, [4096:8192]=x_prop
// =============================================================
__global__ __launch_bounds__(256) void cosine_kernel(
    const float* __restrict__ head_out,  // (8192,300) ent heads
    const float* __restrict__ prop_out,  // (8192,300)
    float* __restrict__ out)             // (8192,)
{
    int w    = blockIdx.x * 4 + (threadIdx.x >> 6);
    int lane = threadIdx.x & 63;
    const float *a, *b;
    if (w < 4096) {
        a = head_out + (size_t)w * 300;
        b = head_out + (size_t)(4096 + w) * 300;
    } else {
        int b2 = w - 4096;
        a = prop_out + (size_t)b2 * 300;
        b = prop_out + (size_t)(4096 + b2) * 300;
    }
    float ab = 0.f, aa = 0.f, bb = 0.f;
    for (int tt = lane; tt < 300; tt += 64) {
        float av = a[tt], bv = b[tt];
        ab += av * bv; aa += av * av; bb += bv * bv;
    }
    #pragma unroll
    for (int d = 1; d < 64; d <<= 1) {
        ab += __shfl_xor(ab, d);
        aa += __shfl_xor(aa, d);
        bb += __shfl_xor(bb, d);
    }
    if (lane == 0) {
        float na = fmaxf(sqrtf(aa), 1e-8f);
        float nb = fmaxf(sqrtf(bb), 1e-8f);
        out[w] = ab / (na * nb);
    }
}

extern "C" void kernel_launch(void* const* d_in, const int* in_sizes, int n_in,
                              void* d_out, int out_size, void* d_ws, size_t ws_size,
                              hipStream_t stream) {
    const int*   inputs      = (const int*)d_in[0];
    const int*   inputs_prop = (const int*)d_in[1];
    const float* emb         = (const float*)d_in[2];
    const float* W_out       = (const float*)d_in[3];
    const float* b_out       = (const float*)d_in[4];
    const float* v           = (const float*)d_in[5];
    const float* W_prop      = (const float*)d_in[6];
    const float* b_prop      = (const float*)d_in[7];
    float* out = (float*)d_out;

    char* ws = (char*)d_ws;
    _Float16* embh = (_Float16*)(ws + EMBH_OFF);
    _Float16* ctxh = (_Float16*)(ws + CTXH_OFF);
    _Float16* Aph  = (_Float16*)(ws + APH_OFF);
    _Float16* Wh   = (_Float16*)(ws + WH_OFF);
    _Float16* Wph  = (_Float16*)(ws + WPH_OFF);
    float* head_out = (float*)(ws + HEAD_OFF);
    float* prop_out = (float*)(ws + PROP_OFF);
    int*   nidx     = (int*)(ws + NIDX_OFF);
    int*   pidx     = (int*)(ws + PIDX_OFF);

    conv_kernel<<<8192, 256, 0, stream>>>(emb, W_out, W_prop, embh, Wh, Wph);
    attend_kernel<<<6144, 256, 0, stream>>>(inputs, inputs_prop, embh, v, ctxh, nidx, pidx, Aph);
    gemm_head_kernel<<<512, 192, 0, stream>>>(embh, ctxh, nidx, Wh, b_out, head_out, Aph);
    gemm_prop_kernel<<<256, 256, 0, stream>>>(Aph, pidx, embh, Wph, b_prop, prop_out);
    cosine_kernel<<<2048, 256, 0, stream>>>(head_out, prop_out, out);
}